// Round 19
// baseline (207.307 us; speedup 1.0000x reference)
//
#include <hip/hip_runtime.h>
#include <hip/hip_cooperative_groups.h>
#include <math.h>

namespace cg = cooperative_groups;

#define G      48
#define NCELLS (G * G * G)        // 110592
#define LOF    (-6.0f)
#define HH     0.25f              // 12/48
#define INVH   4.0f
#define DELTA  1e-3f              // accept slack >> fp d2 rounding (~1e-5)
#define NCHUNK 16                 // final brute ref-chunks per query
#define R2ACC  (HH * HH)                   // knn27 accept radius^2
#define R2ACC5 (4.0f * HH * HH)            // knn125 accept radius^2 (2h)^2
#define PBLK   256                         // prep_all blocks
#define CPB    (NCELLS / PBLK)             // 432 cells per block

__device__ __forceinline__ int cell_coord(float x) {
    int c = (int)floorf((x - LOF) * INVH);
    c = c < 0 ? 0 : c;
    return c > G - 1 ? G - 1 : c;
}
__device__ __forceinline__ int imax2(int a, int b) { return a > b ? a : b; }
__device__ __forceinline__ int imin2(int a, int b) { return a < b ? a : b; }
__device__ __forceinline__ float rdfl(float v) {
    return __int_as_float(__builtin_amdgcn_readfirstlane(__float_as_int(v)));
}

// lexicographic (d, idx) 3-slot insert == jax top_k tie semantics (order-free)
#define LEXINSERT(dv, jv) do {                                        \
    float d_ = (dv); int j_ = (jv);                                   \
    bool l0 = (d_ < e0) || ((d_ == e0) && (j_ < i0));                 \
    bool l1 = (d_ < e1) || ((d_ == e1) && (j_ < i1));                 \
    bool l2 = (d_ < e2) || ((d_ == e2) && (j_ < i2));                 \
    int   ni0 = l0 ? j_ : i0;                                         \
    int   ni1 = l0 ? i0 : (l1 ? j_ : i1);                             \
    int   ni2 = l1 ? i1 : (l2 ? j_ : i2);                             \
    float ne0 = l0 ? d_ : e0;                                         \
    float ne1 = l0 ? e0 : (l1 ? d_ : e1);                             \
    float ne2 = l1 ? e1 : (l2 ? d_ : e2);                             \
    e0 = ne0; e1 = ne1; e2 = ne2; i0 = ni0; i1 = ni1; i2 = ni2;       \
} while (0)

// lanes split refs [lo,hi) of a contiguous run; coalesced float4 loads.
// d2 chain bit-identical to the passing kernels (contract off in caller).
#define SCAN_RUN(lo_, hi_) do {                                       \
    for (int u = (lo_) + lane; u < (hi_); u += 64) {                  \
        float4 rr = srt[u];                                           \
        float xx = rr.x * rr.x;                                       \
        float yy = rr.y * rr.y;                                       \
        float zz = rr.z * rr.z;                                       \
        float r2 = (xx + yy) + zz;                                    \
        float td = qx * rr.x;                                         \
        td = fmaf(qy, rr.y, td);                                      \
        td = fmaf(qz, rr.z, td);                                      \
        float aa = q2 + r2;                                           \
        float dd = fmaf(-2.0f, td, aa);                               \
        int jj = __float_as_int(rr.w);                                \
        LEXINSERT(dd, jj);                                            \
    }                                                                 \
} while (0)

// 64-lane butterfly lex-merge of per-lane top-3 sets
#define MERGE64() do {                                                \
    _Pragma("unroll")                                                 \
    for (int mk_ = 1; mk_ < 64; mk_ <<= 1) {                          \
        float f0 = __shfl_xor(e0, mk_, 64);                           \
        float f1 = __shfl_xor(e1, mk_, 64);                           \
        float f2 = __shfl_xor(e2, mk_, 64);                           \
        int   g0 = __shfl_xor(i0, mk_, 64);                           \
        int   g1 = __shfl_xor(i1, mk_, 64);                           \
        int   g2 = __shfl_xor(i2, mk_, 64);                           \
        LEXINSERT(f0, g0);                                            \
        LEXINSERT(f1, g1);                                            \
        LEXINSERT(f2, g2);                                            \
    }                                                                 \
} while (0)

// 32-lane butterfly: masks 1..16 never cross the 32-lane group boundary, so
// the SAME instructions merge both queries of the wave simultaneously.
#define MERGE32() do {                                                \
    _Pragma("unroll")                                                 \
    for (int mk_ = 1; mk_ < 32; mk_ <<= 1) {                          \
        float f0 = __shfl_xor(e0, mk_, 64);                           \
        float f1 = __shfl_xor(e1, mk_, 64);                           \
        float f2 = __shfl_xor(e2, mk_, 64);                           \
        int   g0 = __shfl_xor(i0, mk_, 64);                           \
        int   g1 = __shfl_xor(i1, mk_, 64);                           \
        int   g2 = __shfl_xor(i2, mk_, 64);                           \
        LEXINSERT(f0, g0);                                            \
        LEXINSERT(f1, g1);                                            \
        LEXINSERT(f2, g2);                                            \
    }                                                                 \
} while (0)

// clamp + weights + gather + store, reference op order
#define EPILOGUE() do {                                               \
    e0 = fmaxf(e0, 0.0f);                                             \
    e1 = fmaxf(e1, 0.0f);                                             \
    e2 = fmaxf(e2, 0.0f);                                             \
    float s0 = sqrtf(e0);                                             \
    float s1 = sqrtf(e1);                                             \
    float s2 = sqrtf(e2);                                             \
    float w0 = 1.0f / (s0 + 1e-8f);                                   \
    float w1 = 1.0f / (s1 + 1e-8f);                                   \
    float w2 = 1.0f / (s2 + 1e-8f);                                   \
    float wsum = (w0 + w1) + w2;                                      \
    w0 = w0 / wsum; w1 = w1 / wsum; w2 = w2 / wsum;                   \
    float f0x = flow[i0*3+0], f0y = flow[i0*3+1], f0z = flow[i0*3+2]; \
    float f1x = flow[i1*3+0], f1y = flow[i1*3+1], f1z = flow[i1*3+2]; \
    float f2x = flow[i2*3+0], f2y = flow[i2*3+1], f2z = flow[i2*3+2]; \
    out[q*3+0] = (w0 * f0x + w1 * f1x) + w2 * f2x;                    \
    out[q*3+1] = (w0 * f0y + w1 * f1y) + w2 * f2y;                    \
    out[q*3+2] = (w0 * f0z + w1 * f1z) + w2 * f2z;                    \
} while (0)

// ---------------------------------------------------------------------------
// Cooperative prep: zero -> count -> two-level parallel scan -> fill, one
// launch, grid.sync between phases (replaces 4 kernels + the 49.7 us serial
// single-block scan measured in R18). grid = 256 blocks x 256 threads
// (1 block/CU, co-resident).
// ---------------------------------------------------------------------------
__global__ __launch_bounds__(256) void prep_all(
    const float* __restrict__ ref, int* __restrict__ cnt,
    int* __restrict__ off, int* __restrict__ cur,
    float4* __restrict__ srt, int* __restrict__ bsum, int Nr) {
    cg::grid_group grid = cg::this_grid();
    int tid  = threadIdx.x;
    int b    = blockIdx.x;
    int gtid = b * PBLK + tid;
    int gsz  = PBLK * PBLK;                       // 65536

    // phase Z: zero cnt (+2 flag slots)
    for (int i = gtid; i < NCELLS + 2; i += gsz) cnt[i] = 0;
    grid.sync();

    // phase C: bin counts
    for (int j = gtid; j < Nr; j += gsz) {
        int cx = cell_coord(ref[3 * j + 0]);
        int cy = cell_coord(ref[3 * j + 1]);
        int cz = cell_coord(ref[3 * j + 2]);
        atomicAdd(&cnt[(cz * G + cy) * G + cx], 1);
    }
    grid.sync();

    // phase S1: block-local scan of this block's 432 cells (2 per thread)
    {
        __shared__ int wt[4];
        int base = b * CPB;
        int v0 = 0, v1 = 0;
        if (tid < CPB / 2) {                       // 216 active threads
            v0 = cnt[base + 2 * tid];
            v1 = cnt[base + 2 * tid + 1];
        }
        int s = v0 + v1;
        int lane = tid & 63, wid = tid >> 6;
        int incl = s;
#pragma unroll
        for (int sh = 1; sh < 64; sh <<= 1) {
            int t = __shfl_up(incl, sh, 64);
            if (lane >= sh) incl += t;
        }
        if (lane == 63) wt[wid] = incl;
        __syncthreads();
        if (tid == 0) {
            int run = 0;
#pragma unroll
            for (int w = 0; w < 4; ++w) { int t = wt[w]; wt[w] = run; run += t; }
        }
        __syncthreads();
        int excl = wt[wid] + incl - s;
        if (tid < CPB / 2) {
            off[base + 2 * tid]     = excl;
            off[base + 2 * tid + 1] = excl + v0;
        }
        if (tid == PBLK - 1) bsum[b] = excl + s;   // block total
    }
    grid.sync();

    // phase S2: block offset = sum of bsum[j<b]; add; write cur
    {
        __shared__ int red[4];
        __shared__ int boffs;
        int lane = tid & 63, wid = tid >> 6;
        int m = (tid < b) ? bsum[tid] : 0;
#pragma unroll
        for (int mk = 1; mk < 64; mk <<= 1) m += __shfl_xor(m, mk, 64);
        if (lane == 0) red[wid] = m;
        __syncthreads();
        if (tid == 0) boffs = red[0] + red[1] + red[2] + red[3];
        __syncthreads();
        int boff = boffs;
        int base = b * CPB;
        for (int i = tid; i < CPB; i += PBLK) {
            int t = off[base + i] + boff;
            off[base + i] = t;
            cur[base + i] = t;
        }
        if (b == PBLK - 1 && tid == PBLK - 1) off[NCELLS] = boff + bsum[b];
    }
    grid.sync();

    // phase F: scatter refs (x,y,z, idx-as-bits)
    for (int j = gtid; j < Nr; j += gsz) {
        float x = ref[3 * j + 0], y = ref[3 * j + 1], z = ref[3 * j + 2];
        int cx = cell_coord(x), cy = cell_coord(y), cz = cell_coord(z);
        int cell = (cz * G + cy) * G + cx;
        int pos = atomicAdd(&cur[cell], 1);
        srt[pos] = make_float4(x, y, z, __int_as_float(j));
    }
}

// u -> srt index via the proven 9-row bijection (p*, b* group-uniform)
#define MAPIDX(u_, out_) do {                                         \
    int t_ = (u_) + b0;                                               \
    t_ = ((u_) >= p1) ? ((u_) + b1) : t_;                             \
    t_ = ((u_) >= p2) ? ((u_) + b2) : t_;                             \
    t_ = ((u_) >= p3) ? ((u_) + b3) : t_;                             \
    t_ = ((u_) >= p4) ? ((u_) + b4) : t_;                             \
    t_ = ((u_) >= p5) ? ((u_) + b5) : t_;                             \
    t_ = ((u_) >= p6) ? ((u_) + b6) : t_;                             \
    t_ = ((u_) >= p7) ? ((u_) + b7) : t_;                             \
    t_ = ((u_) >= p8) ? ((u_) + b8) : t_;                             \
    (out_) = t_;                                                      \
} while (0)

// d2 compute + insert for one loaded float4 (bit-identical chain)
#define BODY(rr_) do {                                                \
    float xx = (rr_).x * (rr_).x;                                     \
    float yy = (rr_).y * (rr_).y;                                     \
    float zz = (rr_).z * (rr_).z;                                     \
    float r2v = (xx + yy) + zz;                                       \
    float td = qx * (rr_).x;                                          \
    td = fmaf(qy, (rr_).y, td);                                       \
    td = fmaf(qz, (rr_).z, td);                                       \
    float aa = q2 + r2v;                                              \
    float dd = fmaf(-2.0f, td, aa);                                   \
    int jj = __float_as_int((rr_).w);                                 \
    LEXINSERT(dd, jj);                                                \
} while (0)

// ---------------------------------------------------------------------------
// 27-cell kNN, TWO queries per wave + 2-deep pipeline (R18-passing verbatim).
// ---------------------------------------------------------------------------
__global__ __launch_bounds__(256) void knn27(
    const float* __restrict__ qpts, const float4* __restrict__ srt,
    const int* __restrict__ off, const float* __restrict__ flow,
    float* __restrict__ out, int* __restrict__ qlist,
    int* __restrict__ nflag, int Nq) {
#pragma clang fp contract(off)
    int sl = threadIdx.x & 31;                     // sub-lane in 32-group
    int q  = blockIdx.x * 8 + (threadIdx.x >> 5);  // 8 queries per 256-block
    bool qv = q < Nq;
    int qc = qv ? q : 0;

    float qx = qpts[3 * qc + 0];                   // same addr across group
    float qy = qpts[3 * qc + 1];
    float qz = qpts[3 * qc + 2];
    float q2 = (qx * qx + qy * qy) + qz * qz;

    int cx = cell_coord(qx), cy = cell_coord(qy), cz = cell_coord(qz);

    int dz = sl / 3 - 1, dy = sl % 3 - 1;          // meaningful for sl<9
    int zr = cz + dz, yr = cy + dy;
    bool vrow = (sl < 9) && qv && (zr >= 0) && (zr < G) && (yr >= 0) && (yr < G);
    int xlo = imax2(cx - 1, 0), xhi = imin2(cx + 1, G - 1);
    int vlo = 0, vhi = 0;
    if (vrow) {
        int rowbase = (zr * G + yr) * G;
        vlo = off[rowbase + xlo];
        vhi = off[rowbase + xhi + 1];
    }
    int cnt = vhi - vlo;

    int incl = cnt;
#pragma unroll
    for (int sh = 1; sh <= 8; sh <<= 1) {
        int t = __shfl_up(incl, sh, 32);
        if (sl >= sh) incl += t;
    }
    int total = __shfl(incl, 8, 32);
    int prex  = incl - cnt;

    int p1 = __shfl(prex, 1, 32), p2 = __shfl(prex, 2, 32);
    int p3 = __shfl(prex, 3, 32), p4 = __shfl(prex, 4, 32);
    int p5 = __shfl(prex, 5, 32), p6 = __shfl(prex, 6, 32);
    int p7 = __shfl(prex, 7, 32), p8 = __shfl(prex, 8, 32);
    int b0 = __shfl(vlo, 0, 32);
    int b1 = __shfl(vlo, 1, 32) - p1;
    int b2 = __shfl(vlo, 2, 32) - p2;
    int b3 = __shfl(vlo, 3, 32) - p3;
    int b4 = __shfl(vlo, 4, 32) - p4;
    int b5 = __shfl(vlo, 5, 32) - p5;
    int b6 = __shfl(vlo, 6, 32) - p6;
    int b7 = __shfl(vlo, 7, 32) - p7;
    int b8 = __shfl(vlo, 8, 32) - p8;

    const float FINF = __builtin_inff();
    float e0 = FINF, e1 = FINF, e2 = FINF;
    int   i0 = 0x7fffffff, i1 = 0x7fffffff, i2 = 0x7fffffff;

    int u = sl;
    if (u < total) {
        int idx;
        MAPIDX(u, idx);
        float4 rr = srt[idx];
        for (u += 32; u < total; u += 32) {
            int idx2;
            MAPIDX(u, idx2);
            float4 rn = srt[idx2];
            BODY(rr);
            rr = rn;
        }
        BODY(rr);
    }

    MERGE32();

    bool ok = (e2 + DELTA < R2ACC);
    if (sl == 0 && qv) {
        if (ok) {
            EPILOGUE();
        } else {
            int pos = atomicAdd(nflag, 1);
            qlist[pos] = q;
        }
    }
}

// ---------------------------------------------------------------------------
// Level 2: 5x5x5 neighborhood, ONE WAVE PER FLAGGED QUERY (R18 verbatim).
// ---------------------------------------------------------------------------
__global__ __launch_bounds__(256) void knn125(
    const float* __restrict__ qpts, const float4* __restrict__ srt,
    const int* __restrict__ off, const int* __restrict__ qlist,
    const int* __restrict__ nflag, const float* __restrict__ flow,
    float* __restrict__ out, int* __restrict__ qlist2,
    int* __restrict__ nflag2) {
#pragma clang fp contract(off)
    int lane = threadIdx.x & 63;
    int wav  = (blockIdx.x * 256 + threadIdx.x) >> 6;
    int nWaves = (gridDim.x * 256) >> 6;
    int n = nflag[0];

    for (int f = wav; f < n; f += nWaves) {
        int q = qlist[f];
        float qx = rdfl(qpts[3 * q + 0]);
        float qy = rdfl(qpts[3 * q + 1]);
        float qz = rdfl(qpts[3 * q + 2]);
        float q2 = (qx * qx + qy * qy) + qz * qz;

        int cx = cell_coord(qx), cy = cell_coord(qy), cz = cell_coord(qz);

        int dz = lane / 5 - 2, dy = lane % 5 - 2;  // meaningful for lane<25
        int zr = cz + dz, yr = cy + dy;
        bool vrow = (lane < 25) && (zr >= 0) && (zr < G) && (yr >= 0) && (yr < G);
        int xlo = imax2(cx - 2, 0), xhi = imin2(cx + 2, G - 1);
        int vlo = 0, vhi = 0;
        if (vrow) {
            int rowbase = (zr * G + yr) * G;
            vlo = off[rowbase + xlo];
            vhi = off[rowbase + xhi + 1];
        }

        const float FINF = __builtin_inff();
        float e0 = FINF, e1 = FINF, e2 = FINF;
        int   i0 = 0x7fffffff, i1 = 0x7fffffff, i2 = 0x7fffffff;

#pragma unroll
        for (int r = 0; r < 25; ++r) {
            int lo = __shfl(vlo, r, 64);
            int hi = __shfl(vhi, r, 64);
            SCAN_RUN(lo, hi);
        }

        MERGE64();                                 // raw (unclamped) merge

        bool ok = (e2 + DELTA < R2ACC5);           // INF -> fail
        if (lane == 0) {
            if (ok) {
                EPILOGUE();
            } else {
                int pos = atomicAdd(nflag2, 1);
                qlist2[pos] = q;
            }
        }
    }
}

// ---------------------------------------------------------------------------
// Final brute (exactness safety net): grid-striding waves over (query,
// ref-chunk) items; per-chunk top-3 to cand. (R18 verbatim.)
// ---------------------------------------------------------------------------
__global__ __launch_bounds__(256) void brute_chunk(
    const float* __restrict__ qpts, const float4* __restrict__ srt,
    const int* __restrict__ qlist2, const int* __restrict__ nflag2,
    float2* __restrict__ cand, int Nr) {
#pragma clang fp contract(off)
    int lane = threadIdx.x & 63;
    int wav  = (blockIdx.x * 256 + threadIdx.x) >> 6;
    int nWaves = (gridDim.x * 256) >> 6;
    int nItems = nflag2[0] * NCHUNK;
    int CS = (Nr + NCHUNK - 1) / NCHUNK;

    for (int item = wav; item < nItems; item += nWaves) {
        int f = item / NCHUNK;
        int chunk = item - f * NCHUNK;
        int q = qlist2[f];
        float qx = rdfl(qpts[3 * q + 0]);
        float qy = rdfl(qpts[3 * q + 1]);
        float qz = rdfl(qpts[3 * q + 2]);
        float q2 = (qx * qx + qy * qy) + qz * qz;

        int lo = chunk * CS;
        int hi = imin2(lo + CS, Nr);

        const float FINF = __builtin_inff();
        float e0 = FINF, e1 = FINF, e2 = FINF;
        int   i0 = 0x7fffffff, i1 = 0x7fffffff, i2 = 0x7fffffff;

        SCAN_RUN(lo, hi);
        MERGE64();

        if (lane == 0) {
            cand[item * 3 + 0] = make_float2(e0, __int_as_float(i0));
            cand[item * 3 + 1] = make_float2(e1, __int_as_float(i1));
            cand[item * 3 + 2] = make_float2(e2, __int_as_float(i2));
        }
    }
}

__global__ __launch_bounds__(256) void brute_merge(
    const int* __restrict__ qlist2, const int* __restrict__ nflag2,
    const float2* __restrict__ cand, const float* __restrict__ flow,
    float* __restrict__ out) {
#pragma clang fp contract(off)
    int lane = threadIdx.x & 63;
    int wav  = (blockIdx.x * 256 + threadIdx.x) >> 6;
    int nWaves = (gridDim.x * 256) >> 6;
    int n = nflag2[0];

    for (int f = wav; f < n; f += nWaves) {
        int q = qlist2[f];
        const float FINF = __builtin_inff();
        float e0 = FINF, e1 = FINF, e2 = FINF;
        int   i0 = 0x7fffffff, i1 = 0x7fffffff, i2 = 0x7fffffff;
        if (lane < 3 * NCHUNK) {
            float2 cc = cand[f * (3 * NCHUNK) + lane];
            e0 = cc.x;
            i0 = __float_as_int(cc.y);
        }
        MERGE64();
        if (lane == 0) EPILOGUE();
    }
}

extern "C" void kernel_launch(void* const* d_in, const int* in_sizes, int n_in,
                              void* d_out, int out_size, void* d_ws, size_t ws_size,
                              hipStream_t stream) {
    const float* qp   = (const float*)d_in[0];
    const float* ref  = (const float*)d_in[1];
    const float* flow = (const float*)d_in[2];
    float* out = (float*)d_out;

    int Nq = in_sizes[0] / 3;
    int Nr = in_sizes[1] / 3;

    char* ws = (char*)d_ws;
    float4* srt = (float4*)ws;                       // Nr float4 (16B aligned)
    size_t o = (size_t)Nr * sizeof(float4);
    int* off    = (int*)(ws + o);  o += (size_t)(NCELLS + 1) * sizeof(int);
    int* cur    = (int*)(ws + o);  o += (size_t)NCELLS * sizeof(int);
    int* cnt    = (int*)(ws + o);  o += (size_t)(NCELLS + 2) * sizeof(int);
    int* nflag  = cnt + NCELLS;                      // zeroed in prep phase Z
    int* nflag2 = cnt + NCELLS + 1;                  // zeroed in prep phase Z
    int* qlist  = (int*)(ws + o);  o += (size_t)Nq * sizeof(int);
    int* qlist2 = (int*)(ws + o);  o += (size_t)Nq * sizeof(int);
    int* bsum   = (int*)(ws + o);  o += (size_t)PBLK * sizeof(int);
    o = (o + 15) & ~(size_t)15;
    float2* cand = (float2*)(ws + o);                // Nq*48 float2 worst case
    o += (size_t)Nq * 3 * NCHUNK * sizeof(float2);

    // one cooperative launch replaces zero/count/scan/fill
    void* args[] = { (void*)&ref, (void*)&cnt, (void*)&off, (void*)&cur,
                     (void*)&srt, (void*)&bsum, (void*)&Nr };
    hipLaunchCooperativeKernel((void*)prep_all, dim3(PBLK), dim3(256),
                               args, 0, stream);

    int nBlocks = (Nq + 7) / 8;                      // 8 queries (groups)/block
    knn27<<<nBlocks, 256, 0, stream>>>(qp, srt, off, flow, out, qlist, nflag, Nq);
    knn125<<<1024, 256, 0, stream>>>(qp, srt, off, qlist, nflag, flow, out,
                                     qlist2, nflag2);
    brute_chunk<<<256, 256, 0, stream>>>(qp, srt, qlist2, nflag2, cand, Nr);
    brute_merge<<<64, 256, 0, stream>>>(qlist2, nflag2, cand, flow, out);
}

// Round 20
// 78.747 us; speedup vs baseline: 2.6326x; 2.6326x over previous
//
#include <hip/hip_runtime.h>
#include <math.h>

#define G      32
#define NCELLS (G * G * G)        // 32768
#define LOF    (-6.0f)
#define HH     0.375f             // 12/32
#define INVH   (1.0f / 0.375f)
#define DELTA  1e-3f              // accept slack >> fp d2 rounding (~1e-5)
#define NCHUNK 16                 // fallback ref-chunks per query
#define R2ACC  (HH * HH)
#define SCB    128                // scan blocks
#define SCC    (NCELLS / SCB)     // 256 cells per scan block

__device__ __forceinline__ int cell_coord(float x) {
    int c = (int)floorf((x - LOF) * INVH);
    c = c < 0 ? 0 : c;
    return c > G - 1 ? G - 1 : c;
}
__device__ __forceinline__ int imax2(int a, int b) { return a > b ? a : b; }
__device__ __forceinline__ int imin2(int a, int b) { return a < b ? a : b; }
__device__ __forceinline__ float rdfl(float v) {
    return __int_as_float(__builtin_amdgcn_readfirstlane(__float_as_int(v)));
}

// lexicographic (d, idx) 3-slot insert == jax top_k tie semantics (order-free)
#define LEXINSERT(dv, jv) do {                                        \
    float d_ = (dv); int j_ = (jv);                                   \
    bool l0 = (d_ < e0) || ((d_ == e0) && (j_ < i0));                 \
    bool l1 = (d_ < e1) || ((d_ == e1) && (j_ < i1));                 \
    bool l2 = (d_ < e2) || ((d_ == e2) && (j_ < i2));                 \
    int   ni0 = l0 ? j_ : i0;                                         \
    int   ni1 = l0 ? i0 : (l1 ? j_ : i1);                             \
    int   ni2 = l1 ? i1 : (l2 ? j_ : i2);                             \
    float ne0 = l0 ? d_ : e0;                                         \
    float ne1 = l0 ? e0 : (l1 ? d_ : e1);                             \
    float ne2 = l1 ? e1 : (l2 ? d_ : e2);                             \
    e0 = ne0; e1 = ne1; e2 = ne2; i0 = ni0; i1 = ni1; i2 = ni2;       \
} while (0)

// lanes split refs [lo,hi) of a contiguous run; coalesced float4 loads.
#define SCAN_RUN(lo_, hi_) do {                                       \
    for (int u = (lo_) + lane; u < (hi_); u += 64) {                  \
        float4 rr = srt[u];                                           \
        float xx = rr.x * rr.x;                                       \
        float yy = rr.y * rr.y;                                       \
        float zz = rr.z * rr.z;                                       \
        float r2 = (xx + yy) + zz;                                    \
        float td = qx * rr.x;                                         \
        td = fmaf(qy, rr.y, td);                                      \
        td = fmaf(qz, rr.z, td);                                      \
        float aa = q2 + r2;                                           \
        float dd = fmaf(-2.0f, td, aa);                               \
        int jj = __float_as_int(rr.w);                                \
        LEXINSERT(dd, jj);                                            \
    }                                                                 \
} while (0)

// 64-lane butterfly lex-merge of per-lane top-3 sets
#define MERGE64() do {                                                \
    _Pragma("unroll")                                                 \
    for (int mk_ = 1; mk_ < 64; mk_ <<= 1) {                          \
        float f0 = __shfl_xor(e0, mk_, 64);                           \
        float f1 = __shfl_xor(e1, mk_, 64);                           \
        float f2 = __shfl_xor(e2, mk_, 64);                           \
        int   g0 = __shfl_xor(i0, mk_, 64);                           \
        int   g1 = __shfl_xor(i1, mk_, 64);                           \
        int   g2 = __shfl_xor(i2, mk_, 64);                           \
        LEXINSERT(f0, g0);                                            \
        LEXINSERT(f1, g1);                                            \
        LEXINSERT(f2, g2);                                            \
    }                                                                 \
} while (0)

// 32-lane butterfly: both queries of the wave share the instructions
#define MERGE32() do {                                                \
    _Pragma("unroll")                                                 \
    for (int mk_ = 1; mk_ < 32; mk_ <<= 1) {                          \
        float f0 = __shfl_xor(e0, mk_, 64);                           \
        float f1 = __shfl_xor(e1, mk_, 64);                           \
        float f2 = __shfl_xor(e2, mk_, 64);                           \
        int   g0 = __shfl_xor(i0, mk_, 64);                           \
        int   g1 = __shfl_xor(i1, mk_, 64);                           \
        int   g2 = __shfl_xor(i2, mk_, 64);                           \
        LEXINSERT(f0, g0);                                            \
        LEXINSERT(f1, g1);                                            \
        LEXINSERT(f2, g2);                                            \
    }                                                                 \
} while (0)

// clamp + weights + gather + store, reference op order
#define EPILOGUE() do {                                               \
    e0 = fmaxf(e0, 0.0f);                                             \
    e1 = fmaxf(e1, 0.0f);                                             \
    e2 = fmaxf(e2, 0.0f);                                             \
    float s0 = sqrtf(e0);                                             \
    float s1 = sqrtf(e1);                                             \
    float s2 = sqrtf(e2);                                             \
    float w0 = 1.0f / (s0 + 1e-8f);                                   \
    float w1 = 1.0f / (s1 + 1e-8f);                                   \
    float w2 = 1.0f / (s2 + 1e-8f);                                   \
    float wsum = (w0 + w1) + w2;                                      \
    w0 = w0 / wsum; w1 = w1 / wsum; w2 = w2 / wsum;                   \
    float f0x = flow[i0*3+0], f0y = flow[i0*3+1], f0z = flow[i0*3+2]; \
    float f1x = flow[i1*3+0], f1y = flow[i1*3+1], f1z = flow[i1*3+2]; \
    float f2x = flow[i2*3+0], f2y = flow[i2*3+1], f2z = flow[i2*3+2]; \
    out[q*3+0] = (w0 * f0x + w1 * f1x) + w2 * f2x;                    \
    out[q*3+1] = (w0 * f0y + w1 * f1y) + w2 * f2y;                    \
    out[q*3+2] = (w0 * f0z + w1 * f1z) + w2 * f2z;                    \
} while (0)

__global__ __launch_bounds__(256) void zero_ints(int* __restrict__ p, int n) {
    int i = blockIdx.x * 256 + threadIdx.x;
    if (i < n) p[i] = 0;
}

__global__ __launch_bounds__(256) void bin_count(
    const float* __restrict__ ref, int* __restrict__ cnt, int Nr) {
    int j = blockIdx.x * 256 + threadIdx.x;
    if (j >= Nr) return;
    int cx = cell_coord(ref[3 * j + 0]);
    int cy = cell_coord(ref[3 * j + 1]);
    int cz = cell_coord(ref[3 * j + 2]);
    atomicAdd(&cnt[(cz * G + cy) * G + cx], 1);
}

// ---------------------------------------------------------------------------
// Parallel hierarchical scan, NO serial carry chain (R18 measured the old
// single-block serial scan at 49.7us @G=48 ~ 15us @G=32).
// scan1: block b scans its 256 cells (1/thread), writes local prefix + bsum.
// scan2: block b reduces bsum[j<b] (one 256-thread masked reduce), adds the
// offset to its span, writes cur; last block writes off[NCELLS].
// ---------------------------------------------------------------------------
__global__ __launch_bounds__(256) void scan1(
    const int* __restrict__ cnt, int* __restrict__ off, int* __restrict__ bsum) {
    __shared__ int wt[4];
    int tid = threadIdx.x, b = blockIdx.x;
    int base = b * SCC;
    int lane = tid & 63, wid = tid >> 6;
    int v = cnt[base + tid];
    int incl = v;
#pragma unroll
    for (int sh = 1; sh < 64; sh <<= 1) {
        int t = __shfl_up(incl, sh, 64);
        if (lane >= sh) incl += t;
    }
    if (lane == 63) wt[wid] = incl;
    __syncthreads();
    if (tid == 0) {
        int run = 0;
#pragma unroll
        for (int w = 0; w < 4; ++w) { int t = wt[w]; wt[w] = run; run += t; }
    }
    __syncthreads();
    int excl = wt[wid] + incl - v;
    off[base + tid] = excl;
    if (tid == SCC - 1) bsum[b] = excl + v;
}

__global__ __launch_bounds__(256) void scan2(
    const int* __restrict__ bsum, int* __restrict__ off, int* __restrict__ cur) {
    __shared__ int red[4];
    __shared__ int bo;
    int tid = threadIdx.x, b = blockIdx.x;
    int lane = tid & 63, wid = tid >> 6;
    int m = (tid < b) ? bsum[tid] : 0;             // b < SCB <= 256
#pragma unroll
    for (int mk = 1; mk < 64; mk <<= 1) m += __shfl_xor(m, mk, 64);
    if (lane == 0) red[wid] = m;
    __syncthreads();
    if (tid == 0) bo = red[0] + red[1] + red[2] + red[3];
    __syncthreads();
    int boff = bo;
    int base = b * SCC;
    int t = off[base + tid] + boff;
    off[base + tid] = t;
    cur[base + tid] = t;
    if (b == SCB - 1 && tid == SCC - 1) off[NCELLS] = boff + bsum[b];
}

// scatter refs: sorted float4 (x,y,z, idx-as-bits)
__global__ __launch_bounds__(256) void bin_fill(
    const float* __restrict__ ref, int* __restrict__ cur,
    float4* __restrict__ srt, int Nr) {
    int j = blockIdx.x * 256 + threadIdx.x;
    if (j >= Nr) return;
    float x = ref[3 * j + 0], y = ref[3 * j + 1], z = ref[3 * j + 2];
    int cx = cell_coord(x), cy = cell_coord(y), cz = cell_coord(z);
    int cell = (cz * G + cy) * G + cx;
    int pos = atomicAdd(&cur[cell], 1);
    srt[pos] = make_float4(x, y, z, __int_as_float(j));
}

// u -> srt index via the proven 9-row bijection (p*, b* group-uniform)
#define MAPIDX(u_, out_) do {                                         \
    int t_ = (u_) + b0;                                               \
    t_ = ((u_) >= p1) ? ((u_) + b1) : t_;                             \
    t_ = ((u_) >= p2) ? ((u_) + b2) : t_;                             \
    t_ = ((u_) >= p3) ? ((u_) + b3) : t_;                             \
    t_ = ((u_) >= p4) ? ((u_) + b4) : t_;                             \
    t_ = ((u_) >= p5) ? ((u_) + b5) : t_;                             \
    t_ = ((u_) >= p6) ? ((u_) + b6) : t_;                             \
    t_ = ((u_) >= p7) ? ((u_) + b7) : t_;                             \
    t_ = ((u_) >= p8) ? ((u_) + b8) : t_;                             \
    (out_) = t_;                                                      \
} while (0)

// d2 compute + insert for one loaded float4 (bit-identical chain)
#define BODY(rr_) do {                                                \
    float xx = (rr_).x * (rr_).x;                                     \
    float yy = (rr_).y * (rr_).y;                                     \
    float zz = (rr_).z * (rr_).z;                                     \
    float r2v = (xx + yy) + zz;                                       \
    float td = qx * (rr_).x;                                          \
    td = fmaf(qy, (rr_).y, td);                                       \
    td = fmaf(qz, (rr_).z, td);                                       \
    float aa = q2 + r2v;                                              \
    float dd = fmaf(-2.0f, td, aa);                                   \
    int jj = __float_as_int((rr_).w);                                 \
    LEXINSERT(dd, jj);                                                \
} while (0)

// ---------------------------------------------------------------------------
// 27-cell kNN, TWO queries per wave + 2-deep pipeline (R16-passing verbatim).
// ---------------------------------------------------------------------------
__global__ __launch_bounds__(256) void knn27(
    const float* __restrict__ qpts, const float4* __restrict__ srt,
    const int* __restrict__ off, const float* __restrict__ flow,
    float* __restrict__ out, int* __restrict__ qlist,
    int* __restrict__ nflag, int Nq) {
#pragma clang fp contract(off)
    int sl = threadIdx.x & 31;                     // sub-lane in 32-group
    int q  = blockIdx.x * 8 + (threadIdx.x >> 5);  // 8 queries per 256-block
    bool qv = q < Nq;
    int qc = qv ? q : 0;

    float qx = qpts[3 * qc + 0];                   // same addr across group
    float qy = qpts[3 * qc + 1];
    float qz = qpts[3 * qc + 2];
    float q2 = (qx * qx + qy * qy) + qz * qz;

    int cx = cell_coord(qx), cy = cell_coord(qy), cz = cell_coord(qz);

    int dz = sl / 3 - 1, dy = sl % 3 - 1;          // meaningful for sl<9
    int zr = cz + dz, yr = cy + dy;
    bool vrow = (sl < 9) && qv && (zr >= 0) && (zr < G) && (yr >= 0) && (yr < G);
    int xlo = imax2(cx - 1, 0), xhi = imin2(cx + 1, G - 1);
    int vlo = 0, vhi = 0;
    if (vrow) {
        int rowbase = (zr * G + yr) * G;
        vlo = off[rowbase + xlo];
        vhi = off[rowbase + xhi + 1];
    }
    int cnt = vhi - vlo;

    int incl = cnt;
#pragma unroll
    for (int sh = 1; sh <= 8; sh <<= 1) {
        int t = __shfl_up(incl, sh, 32);
        if (sl >= sh) incl += t;
    }
    int total = __shfl(incl, 8, 32);
    int prex  = incl - cnt;

    int p1 = __shfl(prex, 1, 32), p2 = __shfl(prex, 2, 32);
    int p3 = __shfl(prex, 3, 32), p4 = __shfl(prex, 4, 32);
    int p5 = __shfl(prex, 5, 32), p6 = __shfl(prex, 6, 32);
    int p7 = __shfl(prex, 7, 32), p8 = __shfl(prex, 8, 32);
    int b0 = __shfl(vlo, 0, 32);
    int b1 = __shfl(vlo, 1, 32) - p1;
    int b2 = __shfl(vlo, 2, 32) - p2;
    int b3 = __shfl(vlo, 3, 32) - p3;
    int b4 = __shfl(vlo, 4, 32) - p4;
    int b5 = __shfl(vlo, 5, 32) - p5;
    int b6 = __shfl(vlo, 6, 32) - p6;
    int b7 = __shfl(vlo, 7, 32) - p7;
    int b8 = __shfl(vlo, 8, 32) - p8;

    const float FINF = __builtin_inff();
    float e0 = FINF, e1 = FINF, e2 = FINF;
    int   i0 = 0x7fffffff, i1 = 0x7fffffff, i2 = 0x7fffffff;

    int u = sl;
    if (u < total) {
        int idx;
        MAPIDX(u, idx);
        float4 rr = srt[idx];
        for (u += 32; u < total; u += 32) {
            int idx2;
            MAPIDX(u, idx2);
            float4 rn = srt[idx2];
            BODY(rr);
            rr = rn;
        }
        BODY(rr);
    }

    MERGE32();

    bool ok = (e2 + DELTA < R2ACC);
    if (sl == 0 && qv) {
        if (ok) {
            EPILOGUE();
        } else {
            int pos = atomicAdd(nflag, 1);
            qlist[pos] = q;
        }
    }
}

// ---------------------------------------------------------------------------
// Fallback stage 1 (R16-passing verbatim): grid-striding waves over (flagged
// query, ref-chunk) items.
// ---------------------------------------------------------------------------
__global__ __launch_bounds__(256) void brute_chunk(
    const float* __restrict__ qpts, const float4* __restrict__ srt,
    const int* __restrict__ qlist, const int* __restrict__ nflag,
    float2* __restrict__ cand, int Nr) {
#pragma clang fp contract(off)
    int lane = threadIdx.x & 63;
    int wav  = (blockIdx.x * 256 + threadIdx.x) >> 6;
    int nWaves = (gridDim.x * 256) >> 6;
    int nItems = nflag[0] * NCHUNK;
    int CS = (Nr + NCHUNK - 1) / NCHUNK;

    for (int item = wav; item < nItems; item += nWaves) {
        int f = item / NCHUNK;
        int chunk = item - f * NCHUNK;
        int q = qlist[f];
        float qx = rdfl(qpts[3 * q + 0]);
        float qy = rdfl(qpts[3 * q + 1]);
        float qz = rdfl(qpts[3 * q + 2]);
        float q2 = (qx * qx + qy * qy) + qz * qz;

        int lo = chunk * CS;
        int hi = imin2(lo + CS, Nr);

        const float FINF = __builtin_inff();
        float e0 = FINF, e1 = FINF, e2 = FINF;
        int   i0 = 0x7fffffff, i1 = 0x7fffffff, i2 = 0x7fffffff;

        SCAN_RUN(lo, hi);
        MERGE64();

        if (lane == 0) {
            cand[item * 3 + 0] = make_float2(e0, __int_as_float(i0));
            cand[item * 3 + 1] = make_float2(e1, __int_as_float(i1));
            cand[item * 3 + 2] = make_float2(e2, __int_as_float(i2));
        }
    }
}

__global__ __launch_bounds__(256) void brute_merge(
    const int* __restrict__ qlist, const int* __restrict__ nflag,
    const float2* __restrict__ cand, const float* __restrict__ flow,
    float* __restrict__ out) {
#pragma clang fp contract(off)
    int lane = threadIdx.x & 63;
    int wav  = (blockIdx.x * 256 + threadIdx.x) >> 6;
    int nWaves = (gridDim.x * 256) >> 6;
    int n = nflag[0];

    for (int f = wav; f < n; f += nWaves) {
        int q = qlist[f];
        const float FINF = __builtin_inff();
        float e0 = FINF, e1 = FINF, e2 = FINF;
        int   i0 = 0x7fffffff, i1 = 0x7fffffff, i2 = 0x7fffffff;
        if (lane < 3 * NCHUNK) {
            float2 cc = cand[f * (3 * NCHUNK) + lane];
            e0 = cc.x;
            i0 = __float_as_int(cc.y);
        }
        MERGE64();
        if (lane == 0) EPILOGUE();
    }
}

extern "C" void kernel_launch(void* const* d_in, const int* in_sizes, int n_in,
                              void* d_out, int out_size, void* d_ws, size_t ws_size,
                              hipStream_t stream) {
    const float* qp   = (const float*)d_in[0];
    const float* ref  = (const float*)d_in[1];
    const float* flow = (const float*)d_in[2];
    float* out = (float*)d_out;

    int Nq = in_sizes[0] / 3;
    int Nr = in_sizes[1] / 3;

    char* ws = (char*)d_ws;
    float4* srt = (float4*)ws;                       // Nr float4 (16B aligned)
    size_t o = (size_t)Nr * sizeof(float4);
    int* off    = (int*)(ws + o);  o += (size_t)(NCELLS + 1) * sizeof(int);
    int* cur    = (int*)(ws + o);  o += (size_t)NCELLS * sizeof(int);
    int* cnt    = (int*)(ws + o);  o += (size_t)(NCELLS + 1) * sizeof(int);
    int* nflag  = cnt + NCELLS;                      // zeroed with cnt
    int* qlist  = (int*)(ws + o);  o += (size_t)Nq * sizeof(int);
    int* bsum   = (int*)(ws + o);  o += (size_t)SCB * sizeof(int);
    o = (o + 15) & ~(size_t)15;
    float2* cand = (float2*)(ws + o);                // Nq*48 float2 worst case
    o += (size_t)Nq * 3 * NCHUNK * sizeof(float2);

    zero_ints<<<(NCELLS + 1 + 255) / 256, 256, 0, stream>>>(cnt, NCELLS + 1);
    bin_count<<<(Nr + 255) / 256, 256, 0, stream>>>(ref, cnt, Nr);
    scan1<<<SCB, 256, 0, stream>>>(cnt, off, bsum);
    scan2<<<SCB, 256, 0, stream>>>(bsum, off, cur);
    bin_fill<<<(Nr + 255) / 256, 256, 0, stream>>>(ref, cur, srt, Nr);

    int nBlocks = (Nq + 7) / 8;                      // 8 queries (groups)/block
    knn27<<<nBlocks, 256, 0, stream>>>(qp, srt, off, flow, out, qlist, nflag, Nq);
    brute_chunk<<<1024, 256, 0, stream>>>(qp, srt, qlist, nflag, cand, Nr);
    brute_merge<<<256, 256, 0, stream>>>(qlist, nflag, cand, flow, out);
}

// Round 21
// 73.685 us; speedup vs baseline: 2.8134x; 1.0687x over previous
//
#include <hip/hip_runtime.h>
#include <math.h>

#define G      32
#define NCELLS (G * G * G)        // 32768
#define TOTC   (2 * NCELLS)       // ref cells + query cells
#define LOF    (-6.0f)
#define HH     0.375f             // 12/32
#define INVH   (1.0f / 0.375f)
#define DELTA  1e-3f              // accept slack >> fp d2 rounding (~1e-5)
#define NCHUNK 16                 // fallback ref-chunks per query
#define R2ACC  (HH * HH)
#define SCB    256                // scan blocks (TOTC / 256)
#define SCC    (TOTC / SCB)       // 256 cells per scan block

__device__ __forceinline__ int cell_coord(float x) {
    int c = (int)floorf((x - LOF) * INVH);
    c = c < 0 ? 0 : c;
    return c > G - 1 ? G - 1 : c;
}
__device__ __forceinline__ int imax2(int a, int b) { return a > b ? a : b; }
__device__ __forceinline__ int imin2(int a, int b) { return a < b ? a : b; }
__device__ __forceinline__ float rdfl(float v) {
    return __int_as_float(__builtin_amdgcn_readfirstlane(__float_as_int(v)));
}

// lexicographic (d, idx) 3-slot insert == jax top_k tie semantics (order-free)
#define LEXINSERT(dv, jv) do {                                        \
    float d_ = (dv); int j_ = (jv);                                   \
    bool l0 = (d_ < e0) || ((d_ == e0) && (j_ < i0));                 \
    bool l1 = (d_ < e1) || ((d_ == e1) && (j_ < i1));                 \
    bool l2 = (d_ < e2) || ((d_ == e2) && (j_ < i2));                 \
    int   ni0 = l0 ? j_ : i0;                                         \
    int   ni1 = l0 ? i0 : (l1 ? j_ : i1);                             \
    int   ni2 = l1 ? i1 : (l2 ? j_ : i2);                             \
    float ne0 = l0 ? d_ : e0;                                         \
    float ne1 = l0 ? e0 : (l1 ? d_ : e1);                             \
    float ne2 = l1 ? e1 : (l2 ? d_ : e2);                             \
    e0 = ne0; e1 = ne1; e2 = ne2; i0 = ni0; i1 = ni1; i2 = ni2;       \
} while (0)

// lanes split refs [lo,hi) of a contiguous run; coalesced float4 loads.
#define SCAN_RUN(lo_, hi_) do {                                       \
    for (int u = (lo_) + lane; u < (hi_); u += 64) {                  \
        float4 rr = srt[u];                                           \
        float xx = rr.x * rr.x;                                       \
        float yy = rr.y * rr.y;                                       \
        float zz = rr.z * rr.z;                                       \
        float r2 = (xx + yy) + zz;                                    \
        float td = qx * rr.x;                                         \
        td = fmaf(qy, rr.y, td);                                      \
        td = fmaf(qz, rr.z, td);                                      \
        float aa = q2 + r2;                                           \
        float dd = fmaf(-2.0f, td, aa);                               \
        int jj = __float_as_int(rr.w);                                \
        LEXINSERT(dd, jj);                                            \
    }                                                                 \
} while (0)

// 64-lane butterfly lex-merge of per-lane top-3 sets
#define MERGE64() do {                                                \
    _Pragma("unroll")                                                 \
    for (int mk_ = 1; mk_ < 64; mk_ <<= 1) {                          \
        float f0 = __shfl_xor(e0, mk_, 64);                           \
        float f1 = __shfl_xor(e1, mk_, 64);                           \
        float f2 = __shfl_xor(e2, mk_, 64);                           \
        int   g0 = __shfl_xor(i0, mk_, 64);                           \
        int   g1 = __shfl_xor(i1, mk_, 64);                           \
        int   g2 = __shfl_xor(i2, mk_, 64);                           \
        LEXINSERT(f0, g0);                                            \
        LEXINSERT(f1, g1);                                            \
        LEXINSERT(f2, g2);                                            \
    }                                                                 \
} while (0)

// 32-lane butterfly: both queries of the wave share the instructions
#define MERGE32() do {                                                \
    _Pragma("unroll")                                                 \
    for (int mk_ = 1; mk_ < 32; mk_ <<= 1) {                          \
        float f0 = __shfl_xor(e0, mk_, 64);                           \
        float f1 = __shfl_xor(e1, mk_, 64);                           \
        float f2 = __shfl_xor(e2, mk_, 64);                           \
        int   g0 = __shfl_xor(i0, mk_, 64);                           \
        int   g1 = __shfl_xor(i1, mk_, 64);                           \
        int   g2 = __shfl_xor(i2, mk_, 64);                           \
        LEXINSERT(f0, g0);                                            \
        LEXINSERT(f1, g1);                                            \
        LEXINSERT(f2, g2);                                            \
    }                                                                 \
} while (0)

// clamp + weights + gather + store, reference op order
#define EPILOGUE() do {                                               \
    e0 = fmaxf(e0, 0.0f);                                             \
    e1 = fmaxf(e1, 0.0f);                                             \
    e2 = fmaxf(e2, 0.0f);                                             \
    float s0 = sqrtf(e0);                                             \
    float s1 = sqrtf(e1);                                             \
    float s2 = sqrtf(e2);                                             \
    float w0 = 1.0f / (s0 + 1e-8f);                                   \
    float w1 = 1.0f / (s1 + 1e-8f);                                   \
    float w2 = 1.0f / (s2 + 1e-8f);                                   \
    float wsum = (w0 + w1) + w2;                                      \
    w0 = w0 / wsum; w1 = w1 / wsum; w2 = w2 / wsum;                   \
    float f0x = flow[i0*3+0], f0y = flow[i0*3+1], f0z = flow[i0*3+2]; \
    float f1x = flow[i1*3+0], f1y = flow[i1*3+1], f1z = flow[i1*3+2]; \
    float f2x = flow[i2*3+0], f2y = flow[i2*3+1], f2z = flow[i2*3+2]; \
    out[q*3+0] = (w0 * f0x + w1 * f1x) + w2 * f2x;                    \
    out[q*3+1] = (w0 * f0y + w1 * f1y) + w2 * f2y;                    \
    out[q*3+2] = (w0 * f0z + w1 * f1z) + w2 * f2z;                    \
} while (0)

__global__ __launch_bounds__(256) void zero_ints(int* __restrict__ p, int n) {
    int i = blockIdx.x * 256 + threadIdx.x;
    if (i < n) p[i] = 0;
}

// fused count: refs into cells [0,NCELLS), queries into [NCELLS, TOTC)
__global__ __launch_bounds__(256) void bin_count2(
    const float* __restrict__ ref, const float* __restrict__ qpts,
    int* __restrict__ cnt, int Nr, int Nq) {
    int j = blockIdx.x * 256 + threadIdx.x;
    if (j < Nr) {
        int cx = cell_coord(ref[3 * j + 0]);
        int cy = cell_coord(ref[3 * j + 1]);
        int cz = cell_coord(ref[3 * j + 2]);
        atomicAdd(&cnt[(cz * G + cy) * G + cx], 1);
    } else if (j < Nr + Nq) {
        int k = j - Nr;
        int cx = cell_coord(qpts[3 * k + 0]);
        int cy = cell_coord(qpts[3 * k + 1]);
        int cz = cell_coord(qpts[3 * k + 2]);
        atomicAdd(&cnt[NCELLS + (cz * G + cy) * G + cx], 1);
    }
}

// parallel hierarchical scan over TOTC cells (R20-proven structure)
__global__ __launch_bounds__(256) void scan1(
    const int* __restrict__ cnt, int* __restrict__ off, int* __restrict__ bsum) {
    __shared__ int wt[4];
    int tid = threadIdx.x, b = blockIdx.x;
    int base = b * SCC;
    int lane = tid & 63, wid = tid >> 6;
    int v = cnt[base + tid];
    int incl = v;
#pragma unroll
    for (int sh = 1; sh < 64; sh <<= 1) {
        int t = __shfl_up(incl, sh, 64);
        if (lane >= sh) incl += t;
    }
    if (lane == 63) wt[wid] = incl;
    __syncthreads();
    if (tid == 0) {
        int run = 0;
#pragma unroll
        for (int w = 0; w < 4; ++w) { int t = wt[w]; wt[w] = run; run += t; }
    }
    __syncthreads();
    int excl = wt[wid] + incl - v;
    off[base + tid] = excl;
    if (tid == SCC - 1) bsum[b] = excl + v;
}

__global__ __launch_bounds__(256) void scan2(
    const int* __restrict__ bsum, int* __restrict__ off, int* __restrict__ cur) {
    __shared__ int red[4];
    __shared__ int bo;
    int tid = threadIdx.x, b = blockIdx.x;
    int lane = tid & 63, wid = tid >> 6;
    int m = (tid < b) ? bsum[tid] : 0;             // b < SCB == 256
#pragma unroll
    for (int mk = 1; mk < 64; mk <<= 1) m += __shfl_xor(m, mk, 64);
    if (lane == 0) red[wid] = m;
    __syncthreads();
    if (tid == 0) bo = red[0] + red[1] + red[2] + red[3];
    __syncthreads();
    int boff = bo;
    int base = b * SCC;
    int t = off[base + tid] + boff;
    off[base + tid] = t;
    cur[base + tid] = t;
    if (b == SCB - 1 && tid == SCC - 1) off[TOTC] = boff + bsum[b];
}

// fused scatter: refs into big[0..Nr) (x,y,z,refidx-bits); queries into
// big[Nr..Nr+Nq) (x,y,z,origq-bits) — query cell offsets start at Nr since
// the scan ran over the concatenated cell array.
__global__ __launch_bounds__(256) void bin_fill2(
    const float* __restrict__ ref, const float* __restrict__ qpts,
    int* __restrict__ cur, float4* __restrict__ big, int Nr, int Nq) {
    int j = blockIdx.x * 256 + threadIdx.x;
    if (j < Nr) {
        float x = ref[3 * j + 0], y = ref[3 * j + 1], z = ref[3 * j + 2];
        int cell = (cell_coord(z) * G + cell_coord(y)) * G + cell_coord(x);
        int pos = atomicAdd(&cur[cell], 1);
        big[pos] = make_float4(x, y, z, __int_as_float(j));
    } else if (j < Nr + Nq) {
        int k = j - Nr;
        float x = qpts[3 * k + 0], y = qpts[3 * k + 1], z = qpts[3 * k + 2];
        int cell = NCELLS + (cell_coord(z) * G + cell_coord(y)) * G + cell_coord(x);
        int pos = atomicAdd(&cur[cell], 1);
        big[pos] = make_float4(x, y, z, __int_as_float(k));
    }
}

// u -> srt index via the proven 9-row bijection (p*, b* group-uniform)
#define MAPIDX(u_, out_) do {                                         \
    int t_ = (u_) + b0;                                               \
    t_ = ((u_) >= p1) ? ((u_) + b1) : t_;                             \
    t_ = ((u_) >= p2) ? ((u_) + b2) : t_;                             \
    t_ = ((u_) >= p3) ? ((u_) + b3) : t_;                             \
    t_ = ((u_) >= p4) ? ((u_) + b4) : t_;                             \
    t_ = ((u_) >= p5) ? ((u_) + b5) : t_;                             \
    t_ = ((u_) >= p6) ? ((u_) + b6) : t_;                             \
    t_ = ((u_) >= p7) ? ((u_) + b7) : t_;                             \
    t_ = ((u_) >= p8) ? ((u_) + b8) : t_;                             \
    (out_) = t_;                                                      \
} while (0)

// d2 compute + insert for one loaded float4 (bit-identical chain)
#define BODY(rr_) do {                                                \
    float xx = (rr_).x * (rr_).x;                                     \
    float yy = (rr_).y * (rr_).y;                                     \
    float zz = (rr_).z * (rr_).z;                                     \
    float r2v = (xx + yy) + zz;                                       \
    float td = qx * (rr_).x;                                          \
    td = fmaf(qy, (rr_).y, td);                                       \
    td = fmaf(qz, (rr_).z, td);                                       \
    float aa = q2 + r2v;                                              \
    float dd = fmaf(-2.0f, td, aa);                                   \
    int jj = __float_as_int((rr_).w);                                 \
    LEXINSERT(dd, jj);                                                \
} while (0)

// ---------------------------------------------------------------------------
// 27-cell kNN over SPATIALLY SORTED queries: group (32 lanes) sq handles
// sorted query big[Nr+sq]; a block's 8 queries share 1-2 cells, so the
// 27-cell working set is L1-resident across the block and wave iteration
// counts are balanced. Scatter-write to out[orig]. Otherwise R16-verbatim.
// ---------------------------------------------------------------------------
__global__ __launch_bounds__(256) void knn27(
    const float4* __restrict__ big, const int* __restrict__ off,
    const float* __restrict__ flow, float* __restrict__ out,
    int* __restrict__ qlist, int* __restrict__ nflag, int Nr, int Nq) {
#pragma clang fp contract(off)
    const float4* __restrict__ srt = big;          // refs region
    int sl = threadIdx.x & 31;                     // sub-lane in 32-group
    int sq = blockIdx.x * 8 + (threadIdx.x >> 5);  // sorted query index
    bool qv = sq < Nq;
    int sqc = qv ? sq : 0;

    float4 qq = big[(size_t)Nr + sqc];             // broadcast across group
    float qx = qq.x, qy = qq.y, qz = qq.z;
    int   q  = __float_as_int(qq.w);               // original query index
    float q2 = (qx * qx + qy * qy) + qz * qz;

    int cx = cell_coord(qx), cy = cell_coord(qy), cz = cell_coord(qz);

    int dz = sl / 3 - 1, dy = sl % 3 - 1;          // meaningful for sl<9
    int zr = cz + dz, yr = cy + dy;
    bool vrow = (sl < 9) && qv && (zr >= 0) && (zr < G) && (yr >= 0) && (yr < G);
    int xlo = imax2(cx - 1, 0), xhi = imin2(cx + 1, G - 1);
    int vlo = 0, vhi = 0;
    if (vrow) {
        int rowbase = (zr * G + yr) * G;
        vlo = off[rowbase + xlo];
        vhi = off[rowbase + xhi + 1];
    }
    int cnt = vhi - vlo;

    int incl = cnt;
#pragma unroll
    for (int sh = 1; sh <= 8; sh <<= 1) {
        int t = __shfl_up(incl, sh, 32);
        if (sl >= sh) incl += t;
    }
    int total = __shfl(incl, 8, 32);
    int prex  = incl - cnt;

    int p1 = __shfl(prex, 1, 32), p2 = __shfl(prex, 2, 32);
    int p3 = __shfl(prex, 3, 32), p4 = __shfl(prex, 4, 32);
    int p5 = __shfl(prex, 5, 32), p6 = __shfl(prex, 6, 32);
    int p7 = __shfl(prex, 7, 32), p8 = __shfl(prex, 8, 32);
    int b0 = __shfl(vlo, 0, 32);
    int b1 = __shfl(vlo, 1, 32) - p1;
    int b2 = __shfl(vlo, 2, 32) - p2;
    int b3 = __shfl(vlo, 3, 32) - p3;
    int b4 = __shfl(vlo, 4, 32) - p4;
    int b5 = __shfl(vlo, 5, 32) - p5;
    int b6 = __shfl(vlo, 6, 32) - p6;
    int b7 = __shfl(vlo, 7, 32) - p7;
    int b8 = __shfl(vlo, 8, 32) - p8;

    const float FINF = __builtin_inff();
    float e0 = FINF, e1 = FINF, e2 = FINF;
    int   i0 = 0x7fffffff, i1 = 0x7fffffff, i2 = 0x7fffffff;

    int u = sl;
    if (u < total) {
        int idx;
        MAPIDX(u, idx);
        float4 rr = srt[idx];
        for (u += 32; u < total; u += 32) {
            int idx2;
            MAPIDX(u, idx2);
            float4 rn = srt[idx2];
            BODY(rr);
            rr = rn;
        }
        BODY(rr);
    }

    MERGE32();

    bool ok = (e2 + DELTA < R2ACC);
    if (sl == 0 && qv) {
        if (ok) {
            EPILOGUE();
        } else {
            int pos = atomicAdd(nflag, 1);
            qlist[pos] = q;                        // original index
        }
    }
}

// ---------------------------------------------------------------------------
// Fallback stage 1 (R16-passing verbatim): grid-striding waves over (flagged
// query, ref-chunk) items; reads original qpts.
// ---------------------------------------------------------------------------
__global__ __launch_bounds__(256) void brute_chunk(
    const float* __restrict__ qpts, const float4* __restrict__ srt,
    const int* __restrict__ qlist, const int* __restrict__ nflag,
    float2* __restrict__ cand, int Nr) {
#pragma clang fp contract(off)
    int lane = threadIdx.x & 63;
    int wav  = (blockIdx.x * 256 + threadIdx.x) >> 6;
    int nWaves = (gridDim.x * 256) >> 6;
    int nItems = nflag[0] * NCHUNK;
    int CS = (Nr + NCHUNK - 1) / NCHUNK;

    for (int item = wav; item < nItems; item += nWaves) {
        int f = item / NCHUNK;
        int chunk = item - f * NCHUNK;
        int q = qlist[f];
        float qx = rdfl(qpts[3 * q + 0]);
        float qy = rdfl(qpts[3 * q + 1]);
        float qz = rdfl(qpts[3 * q + 2]);
        float q2 = (qx * qx + qy * qy) + qz * qz;

        int lo = chunk * CS;
        int hi = imin2(lo + CS, Nr);

        const float FINF = __builtin_inff();
        float e0 = FINF, e1 = FINF, e2 = FINF;
        int   i0 = 0x7fffffff, i1 = 0x7fffffff, i2 = 0x7fffffff;

        SCAN_RUN(lo, hi);
        MERGE64();

        if (lane == 0) {
            cand[item * 3 + 0] = make_float2(e0, __int_as_float(i0));
            cand[item * 3 + 1] = make_float2(e1, __int_as_float(i1));
            cand[item * 3 + 2] = make_float2(e2, __int_as_float(i2));
        }
    }
}

__global__ __launch_bounds__(256) void brute_merge(
    const int* __restrict__ qlist, const int* __restrict__ nflag,
    const float2* __restrict__ cand, const float* __restrict__ flow,
    float* __restrict__ out) {
#pragma clang fp contract(off)
    int lane = threadIdx.x & 63;
    int wav  = (blockIdx.x * 256 + threadIdx.x) >> 6;
    int nWaves = (gridDim.x * 256) >> 6;
    int n = nflag[0];

    for (int f = wav; f < n; f += nWaves) {
        int q = qlist[f];
        const float FINF = __builtin_inff();
        float e0 = FINF, e1 = FINF, e2 = FINF;
        int   i0 = 0x7fffffff, i1 = 0x7fffffff, i2 = 0x7fffffff;
        if (lane < 3 * NCHUNK) {
            float2 cc = cand[f * (3 * NCHUNK) + lane];
            e0 = cc.x;
            i0 = __float_as_int(cc.y);
        }
        MERGE64();
        if (lane == 0) EPILOGUE();
    }
}

extern "C" void kernel_launch(void* const* d_in, const int* in_sizes, int n_in,
                              void* d_out, int out_size, void* d_ws, size_t ws_size,
                              hipStream_t stream) {
    const float* qp   = (const float*)d_in[0];
    const float* ref  = (const float*)d_in[1];
    const float* flow = (const float*)d_in[2];
    float* out = (float*)d_out;

    int Nq = in_sizes[0] / 3;
    int Nr = in_sizes[1] / 3;

    char* ws = (char*)d_ws;
    float4* big = (float4*)ws;                       // (Nr+Nq) float4
    size_t o = (size_t)(Nr + Nq) * sizeof(float4);
    int* off    = (int*)(ws + o);  o += (size_t)(TOTC + 1) * sizeof(int);
    int* cur    = (int*)(ws + o);  o += (size_t)TOTC * sizeof(int);
    int* cnt    = (int*)(ws + o);  o += (size_t)(TOTC + 1) * sizeof(int);
    int* nflag  = cnt + TOTC;                        // zeroed with cnt
    int* qlist  = (int*)(ws + o);  o += (size_t)Nq * sizeof(int);
    int* bsum   = (int*)(ws + o);  o += (size_t)SCB * sizeof(int);
    o = (o + 15) & ~(size_t)15;
    float2* cand = (float2*)(ws + o);                // Nq*48 float2 worst case
    o += (size_t)Nq * 3 * NCHUNK * sizeof(float2);

    zero_ints<<<(TOTC + 1 + 255) / 256, 256, 0, stream>>>(cnt, TOTC + 1);
    bin_count2<<<(Nr + Nq + 255) / 256, 256, 0, stream>>>(ref, qp, cnt, Nr, Nq);
    scan1<<<SCB, 256, 0, stream>>>(cnt, off, bsum);
    scan2<<<SCB, 256, 0, stream>>>(bsum, off, cur);
    bin_fill2<<<(Nr + Nq + 255) / 256, 256, 0, stream>>>(ref, qp, cur, big, Nr, Nq);

    int nBlocks = (Nq + 7) / 8;                      // 8 sorted queries/block
    knn27<<<nBlocks, 256, 0, stream>>>(big, off, flow, out, qlist, nflag, Nr, Nq);
    brute_chunk<<<1024, 256, 0, stream>>>(qp, big, qlist, nflag, cand, Nr);
    brute_merge<<<256, 256, 0, stream>>>(qlist, nflag, cand, flow, out);
}

// Round 22
// 71.280 us; speedup vs baseline: 2.9083x; 1.0337x over previous
//
#include <hip/hip_runtime.h>
#include <math.h>

#define G      32
#define NCELLS (G * G * G)        // 32768
#define TOTC   (2 * NCELLS)       // ref cells + query cells
#define LOF    (-6.0f)
#define HH     0.375f             // 12/32
#define INVH   (1.0f / 0.375f)
#define DELTA  1e-3f              // accept slack >> fp d2 rounding (~1e-5)
#define R2ACC  (HH * HH)
#define SCB    256                // scan blocks (TOTC / 256)
#define SCC    (TOTC / SCB)       // 256 cells per scan block

__device__ __forceinline__ int cell_coord(float x) {
    int c = (int)floorf((x - LOF) * INVH);
    c = c < 0 ? 0 : c;
    return c > G - 1 ? G - 1 : c;
}
__device__ __forceinline__ int imax2(int a, int b) { return a > b ? a : b; }
__device__ __forceinline__ int imin2(int a, int b) { return a < b ? a : b; }
__device__ __forceinline__ float rdfl(float v) {
    return __int_as_float(__builtin_amdgcn_readfirstlane(__float_as_int(v)));
}

// lexicographic (d, idx) 3-slot insert == jax top_k tie semantics (order-free)
#define LEXINSERT(dv, jv) do {                                        \
    float d_ = (dv); int j_ = (jv);                                   \
    bool l0 = (d_ < e0) || ((d_ == e0) && (j_ < i0));                 \
    bool l1 = (d_ < e1) || ((d_ == e1) && (j_ < i1));                 \
    bool l2 = (d_ < e2) || ((d_ == e2) && (j_ < i2));                 \
    int   ni0 = l0 ? j_ : i0;                                         \
    int   ni1 = l0 ? i0 : (l1 ? j_ : i1);                             \
    int   ni2 = l1 ? i1 : (l2 ? j_ : i2);                             \
    float ne0 = l0 ? d_ : e0;                                         \
    float ne1 = l0 ? e0 : (l1 ? d_ : e1);                             \
    float ne2 = l1 ? e1 : (l2 ? d_ : e2);                             \
    e0 = ne0; e1 = ne1; e2 = ne2; i0 = ni0; i1 = ni1; i2 = ni2;       \
} while (0)

// lanes split refs [lo,hi) of a contiguous run; coalesced float4 loads.
#define SCAN_RUN(lo_, hi_) do {                                       \
    for (int u = (lo_) + lane; u < (hi_); u += 64) {                  \
        float4 rr = srt[u];                                           \
        float xx = rr.x * rr.x;                                       \
        float yy = rr.y * rr.y;                                       \
        float zz = rr.z * rr.z;                                       \
        float r2 = (xx + yy) + zz;                                    \
        float td = qx * rr.x;                                         \
        td = fmaf(qy, rr.y, td);                                      \
        td = fmaf(qz, rr.z, td);                                      \
        float aa = q2 + r2;                                           \
        float dd = fmaf(-2.0f, td, aa);                               \
        int jj = __float_as_int(rr.w);                                \
        LEXINSERT(dd, jj);                                            \
    }                                                                 \
} while (0)

// 64-lane butterfly lex-merge of per-lane top-3 sets
#define MERGE64() do {                                                \
    _Pragma("unroll")                                                 \
    for (int mk_ = 1; mk_ < 64; mk_ <<= 1) {                          \
        float f0 = __shfl_xor(e0, mk_, 64);                           \
        float f1 = __shfl_xor(e1, mk_, 64);                           \
        float f2 = __shfl_xor(e2, mk_, 64);                           \
        int   g0 = __shfl_xor(i0, mk_, 64);                           \
        int   g1 = __shfl_xor(i1, mk_, 64);                           \
        int   g2 = __shfl_xor(i2, mk_, 64);                           \
        LEXINSERT(f0, g0);                                            \
        LEXINSERT(f1, g1);                                            \
        LEXINSERT(f2, g2);                                            \
    }                                                                 \
} while (0)

// 32-lane butterfly: both queries of the wave share the instructions
#define MERGE32() do {                                                \
    _Pragma("unroll")                                                 \
    for (int mk_ = 1; mk_ < 32; mk_ <<= 1) {                          \
        float f0 = __shfl_xor(e0, mk_, 64);                           \
        float f1 = __shfl_xor(e1, mk_, 64);                           \
        float f2 = __shfl_xor(e2, mk_, 64);                           \
        int   g0 = __shfl_xor(i0, mk_, 64);                           \
        int   g1 = __shfl_xor(i1, mk_, 64);                           \
        int   g2 = __shfl_xor(i2, mk_, 64);                           \
        LEXINSERT(f0, g0);                                            \
        LEXINSERT(f1, g1);                                            \
        LEXINSERT(f2, g2);                                            \
    }                                                                 \
} while (0)

// clamp + weights + gather + store, reference op order
#define EPILOGUE() do {                                               \
    e0 = fmaxf(e0, 0.0f);                                             \
    e1 = fmaxf(e1, 0.0f);                                             \
    e2 = fmaxf(e2, 0.0f);                                             \
    float s0 = sqrtf(e0);                                             \
    float s1 = sqrtf(e1);                                             \
    float s2 = sqrtf(e2);                                             \
    float w0 = 1.0f / (s0 + 1e-8f);                                   \
    float w1 = 1.0f / (s1 + 1e-8f);                                   \
    float w2 = 1.0f / (s2 + 1e-8f);                                   \
    float wsum = (w0 + w1) + w2;                                      \
    w0 = w0 / wsum; w1 = w1 / wsum; w2 = w2 / wsum;                   \
    float f0x = flow[i0*3+0], f0y = flow[i0*3+1], f0z = flow[i0*3+2]; \
    float f1x = flow[i1*3+0], f1y = flow[i1*3+1], f1z = flow[i1*3+2]; \
    float f2x = flow[i2*3+0], f2y = flow[i2*3+1], f2z = flow[i2*3+2]; \
    out[q*3+0] = (w0 * f0x + w1 * f1x) + w2 * f2x;                    \
    out[q*3+1] = (w0 * f0y + w1 * f1y) + w2 * f2y;                    \
    out[q*3+2] = (w0 * f0z + w1 * f1z) + w2 * f2z;                    \
} while (0)

__global__ __launch_bounds__(256) void zero_ints(int* __restrict__ p, int n) {
    int i = blockIdx.x * 256 + threadIdx.x;
    if (i < n) p[i] = 0;
}

// fused count: refs into cells [0,NCELLS), queries into [NCELLS, TOTC)
__global__ __launch_bounds__(256) void bin_count2(
    const float* __restrict__ ref, const float* __restrict__ qpts,
    int* __restrict__ cnt, int Nr, int Nq) {
    int j = blockIdx.x * 256 + threadIdx.x;
    if (j < Nr) {
        int cx = cell_coord(ref[3 * j + 0]);
        int cy = cell_coord(ref[3 * j + 1]);
        int cz = cell_coord(ref[3 * j + 2]);
        atomicAdd(&cnt[(cz * G + cy) * G + cx], 1);
    } else if (j < Nr + Nq) {
        int k = j - Nr;
        int cx = cell_coord(qpts[3 * k + 0]);
        int cy = cell_coord(qpts[3 * k + 1]);
        int cz = cell_coord(qpts[3 * k + 2]);
        atomicAdd(&cnt[NCELLS + (cz * G + cy) * G + cx], 1);
    }
}

// parallel hierarchical scan over TOTC cells (R20-proven structure)
__global__ __launch_bounds__(256) void scan1(
    const int* __restrict__ cnt, int* __restrict__ off, int* __restrict__ bsum) {
    __shared__ int wt[4];
    int tid = threadIdx.x, b = blockIdx.x;
    int base = b * SCC;
    int lane = tid & 63, wid = tid >> 6;
    int v = cnt[base + tid];
    int incl = v;
#pragma unroll
    for (int sh = 1; sh < 64; sh <<= 1) {
        int t = __shfl_up(incl, sh, 64);
        if (lane >= sh) incl += t;
    }
    if (lane == 63) wt[wid] = incl;
    __syncthreads();
    if (tid == 0) {
        int run = 0;
#pragma unroll
        for (int w = 0; w < 4; ++w) { int t = wt[w]; wt[w] = run; run += t; }
    }
    __syncthreads();
    int excl = wt[wid] + incl - v;
    off[base + tid] = excl;
    if (tid == SCC - 1) bsum[b] = excl + v;
}

// scan2 also zeroes the nflag counter (block 0) — saves zeroing it upstream
__global__ __launch_bounds__(256) void scan2(
    const int* __restrict__ bsum, int* __restrict__ off, int* __restrict__ cur,
    int* __restrict__ nflag) {
    __shared__ int red[4];
    __shared__ int bo;
    int tid = threadIdx.x, b = blockIdx.x;
    int lane = tid & 63, wid = tid >> 6;
    if (b == 0 && tid == 0) nflag[0] = 0;
    int m = (tid < b) ? bsum[tid] : 0;             // b < SCB == 256
#pragma unroll
    for (int mk = 1; mk < 64; mk <<= 1) m += __shfl_xor(m, mk, 64);
    if (lane == 0) red[wid] = m;
    __syncthreads();
    if (tid == 0) bo = red[0] + red[1] + red[2] + red[3];
    __syncthreads();
    int boff = bo;
    int base = b * SCC;
    int t = off[base + tid] + boff;
    off[base + tid] = t;
    cur[base + tid] = t;
    if (b == SCB - 1 && tid == SCC - 1) off[TOTC] = boff + bsum[b];
}

// fused scatter: refs into big[0..Nr); queries into big[Nr..Nr+Nq)
__global__ __launch_bounds__(256) void bin_fill2(
    const float* __restrict__ ref, const float* __restrict__ qpts,
    int* __restrict__ cur, float4* __restrict__ big, int Nr, int Nq) {
    int j = blockIdx.x * 256 + threadIdx.x;
    if (j < Nr) {
        float x = ref[3 * j + 0], y = ref[3 * j + 1], z = ref[3 * j + 2];
        int cell = (cell_coord(z) * G + cell_coord(y)) * G + cell_coord(x);
        int pos = atomicAdd(&cur[cell], 1);
        big[pos] = make_float4(x, y, z, __int_as_float(j));
    } else if (j < Nr + Nq) {
        int k = j - Nr;
        float x = qpts[3 * k + 0], y = qpts[3 * k + 1], z = qpts[3 * k + 2];
        int cell = NCELLS + (cell_coord(z) * G + cell_coord(y)) * G + cell_coord(x);
        int pos = atomicAdd(&cur[cell], 1);
        big[pos] = make_float4(x, y, z, __int_as_float(k));
    }
}

// u -> srt index via the proven 9-row bijection (p*, b* group-uniform)
#define MAPIDX(u_, out_) do {                                         \
    int t_ = (u_) + b0;                                               \
    t_ = ((u_) >= p1) ? ((u_) + b1) : t_;                             \
    t_ = ((u_) >= p2) ? ((u_) + b2) : t_;                             \
    t_ = ((u_) >= p3) ? ((u_) + b3) : t_;                             \
    t_ = ((u_) >= p4) ? ((u_) + b4) : t_;                             \
    t_ = ((u_) >= p5) ? ((u_) + b5) : t_;                             \
    t_ = ((u_) >= p6) ? ((u_) + b6) : t_;                             \
    t_ = ((u_) >= p7) ? ((u_) + b7) : t_;                             \
    t_ = ((u_) >= p8) ? ((u_) + b8) : t_;                             \
    (out_) = t_;                                                      \
} while (0)

// d2 compute + insert for one loaded float4 (bit-identical chain)
#define BODY(rr_) do {                                                \
    float xx = (rr_).x * (rr_).x;                                     \
    float yy = (rr_).y * (rr_).y;                                     \
    float zz = (rr_).z * (rr_).z;                                     \
    float r2v = (xx + yy) + zz;                                       \
    float td = qx * (rr_).x;                                          \
    td = fmaf(qy, (rr_).y, td);                                       \
    td = fmaf(qz, (rr_).z, td);                                       \
    float aa = q2 + r2v;                                              \
    float dd = fmaf(-2.0f, td, aa);                                   \
    int jj = __float_as_int((rr_).w);                                 \
    LEXINSERT(dd, jj);                                                \
} while (0)

// ---------------------------------------------------------------------------
// 27-cell kNN over spatially sorted queries (R21-passing verbatim).
// ---------------------------------------------------------------------------
__global__ __launch_bounds__(256) void knn27(
    const float4* __restrict__ big, const int* __restrict__ off,
    const float* __restrict__ flow, float* __restrict__ out,
    int* __restrict__ qlist, int* __restrict__ nflag, int Nr, int Nq) {
#pragma clang fp contract(off)
    const float4* __restrict__ srt = big;          // refs region
    int sl = threadIdx.x & 31;                     // sub-lane in 32-group
    int sq = blockIdx.x * 8 + (threadIdx.x >> 5);  // sorted query index
    bool qv = sq < Nq;
    int sqc = qv ? sq : 0;

    float4 qq = big[(size_t)Nr + sqc];             // broadcast across group
    float qx = qq.x, qy = qq.y, qz = qq.z;
    int   q  = __float_as_int(qq.w);               // original query index
    float q2 = (qx * qx + qy * qy) + qz * qz;

    int cx = cell_coord(qx), cy = cell_coord(qy), cz = cell_coord(qz);

    int dz = sl / 3 - 1, dy = sl % 3 - 1;          // meaningful for sl<9
    int zr = cz + dz, yr = cy + dy;
    bool vrow = (sl < 9) && qv && (zr >= 0) && (zr < G) && (yr >= 0) && (yr < G);
    int xlo = imax2(cx - 1, 0), xhi = imin2(cx + 1, G - 1);
    int vlo = 0, vhi = 0;
    if (vrow) {
        int rowbase = (zr * G + yr) * G;
        vlo = off[rowbase + xlo];
        vhi = off[rowbase + xhi + 1];
    }
    int cnt = vhi - vlo;

    int incl = cnt;
#pragma unroll
    for (int sh = 1; sh <= 8; sh <<= 1) {
        int t = __shfl_up(incl, sh, 32);
        if (sl >= sh) incl += t;
    }
    int total = __shfl(incl, 8, 32);
    int prex  = incl - cnt;

    int p1 = __shfl(prex, 1, 32), p2 = __shfl(prex, 2, 32);
    int p3 = __shfl(prex, 3, 32), p4 = __shfl(prex, 4, 32);
    int p5 = __shfl(prex, 5, 32), p6 = __shfl(prex, 6, 32);
    int p7 = __shfl(prex, 7, 32), p8 = __shfl(prex, 8, 32);
    int b0 = __shfl(vlo, 0, 32);
    int b1 = __shfl(vlo, 1, 32) - p1;
    int b2 = __shfl(vlo, 2, 32) - p2;
    int b3 = __shfl(vlo, 3, 32) - p3;
    int b4 = __shfl(vlo, 4, 32) - p4;
    int b5 = __shfl(vlo, 5, 32) - p5;
    int b6 = __shfl(vlo, 6, 32) - p6;
    int b7 = __shfl(vlo, 7, 32) - p7;
    int b8 = __shfl(vlo, 8, 32) - p8;

    const float FINF = __builtin_inff();
    float e0 = FINF, e1 = FINF, e2 = FINF;
    int   i0 = 0x7fffffff, i1 = 0x7fffffff, i2 = 0x7fffffff;

    int u = sl;
    if (u < total) {
        int idx;
        MAPIDX(u, idx);
        float4 rr = srt[idx];
        for (u += 32; u < total; u += 32) {
            int idx2;
            MAPIDX(u, idx2);
            float4 rn = srt[idx2];
            BODY(rr);
            rr = rn;
        }
        BODY(rr);
    }

    MERGE32();

    bool ok = (e2 + DELTA < R2ACC);
    if (sl == 0 && qv) {
        if (ok) {
            EPILOGUE();
        } else {
            int pos = atomicAdd(nflag, 1);
            qlist[pos] = q;                        // original index
        }
    }
}

// ---------------------------------------------------------------------------
// Fused brute fallback: ONE BLOCK (4 waves) per flagged query. Each wave
// scans a Nr/4 slice coalesced; LDS cross-wave lex-merge; wave-0 epilogue.
// Replaces brute_chunk+brute_merge (one launch, no cand round-trip). Exact:
// union of wave top-3 supersets global top-3; LEXINSERT order-free.
// ---------------------------------------------------------------------------
__global__ __launch_bounds__(256) void brute_block(
    const float* __restrict__ qpts, const float4* __restrict__ srt,
    const int* __restrict__ qlist, const int* __restrict__ nflag,
    const float* __restrict__ flow, float* __restrict__ out, int Nr) {
#pragma clang fp contract(off)
    __shared__ float sd[12];
    __shared__ int   si[12];
    int tid = threadIdx.x;
    int lane = tid & 63, wv = tid >> 6;
    int n = nflag[0];

    for (int f = blockIdx.x; f < n; f += gridDim.x) {
        int q = qlist[f];
        float qx = rdfl(qpts[3 * q + 0]);
        float qy = rdfl(qpts[3 * q + 1]);
        float qz = rdfl(qpts[3 * q + 2]);
        float q2 = (qx * qx + qy * qy) + qz * qz;

        int CS = (Nr + 3) / 4;
        int lo = wv * CS;
        int hi = imin2(lo + CS, Nr);

        const float FINF = __builtin_inff();
        float e0 = FINF, e1 = FINF, e2 = FINF;
        int   i0 = 0x7fffffff, i1 = 0x7fffffff, i2 = 0x7fffffff;

        SCAN_RUN(lo, hi);
        MERGE64();

        if (lane == 0) {
            sd[wv * 3 + 0] = e0; si[wv * 3 + 0] = i0;
            sd[wv * 3 + 1] = e1; si[wv * 3 + 1] = i1;
            sd[wv * 3 + 2] = e2; si[wv * 3 + 2] = i2;
        }
        __syncthreads();
        if (wv == 0) {
            e0 = e1 = e2 = FINF;
            i0 = i1 = i2 = 0x7fffffff;
            if (lane < 12) { e0 = sd[lane]; i0 = si[lane]; }
            MERGE64();
            if (lane == 0) EPILOGUE();
        }
        __syncthreads();
    }
}

extern "C" void kernel_launch(void* const* d_in, const int* in_sizes, int n_in,
                              void* d_out, int out_size, void* d_ws, size_t ws_size,
                              hipStream_t stream) {
    const float* qp   = (const float*)d_in[0];
    const float* ref  = (const float*)d_in[1];
    const float* flow = (const float*)d_in[2];
    float* out = (float*)d_out;

    int Nq = in_sizes[0] / 3;
    int Nr = in_sizes[1] / 3;

    char* ws = (char*)d_ws;
    float4* big = (float4*)ws;                       // (Nr+Nq) float4
    size_t o = (size_t)(Nr + Nq) * sizeof(float4);
    int* off    = (int*)(ws + o);  o += (size_t)(TOTC + 1) * sizeof(int);
    int* cur    = (int*)(ws + o);  o += (size_t)TOTC * sizeof(int);
    int* cnt    = (int*)(ws + o);  o += (size_t)TOTC * sizeof(int);
    int* nflag  = (int*)(ws + o);  o += sizeof(int); // zeroed by scan2
    int* qlist  = (int*)(ws + o);  o += (size_t)Nq * sizeof(int);
    int* bsum   = (int*)(ws + o);  o += (size_t)SCB * sizeof(int);

    zero_ints<<<(TOTC + 255) / 256, 256, 0, stream>>>(cnt, TOTC);
    bin_count2<<<(Nr + Nq + 255) / 256, 256, 0, stream>>>(ref, qp, cnt, Nr, Nq);
    scan1<<<SCB, 256, 0, stream>>>(cnt, off, bsum);
    scan2<<<SCB, 256, 0, stream>>>(bsum, off, cur, nflag);
    bin_fill2<<<(Nr + Nq + 255) / 256, 256, 0, stream>>>(ref, qp, cur, big, Nr, Nq);

    int nBlocks = (Nq + 7) / 8;                      // 8 sorted queries/block
    knn27<<<nBlocks, 256, 0, stream>>>(big, off, flow, out, qlist, nflag, Nr, Nq);
    brute_block<<<1024, 256, 0, stream>>>(qp, big, qlist, nflag, flow, out, Nr);
}